// Round 1
// 74.833 us; speedup vs baseline: 1.0132x; 1.0132x over previous
//
#include <hip/hip_runtime.h>

#define N_   256
#define IN_  32
#define OUT_ 32
#define BS_  32

// ---------------------------------------------------------------------------
// Fully fused kernel: block = (s, og) with og = group of 4 output channels.
// grid 256 = (s: 32) x (og: 8).  256 threads.  No workspace use at all.
//
// Phase 0: stage perm, xp[a][i] = x[s, perm[a], i]  (36-padded rows),
//          wdt[u][o_l*32+i] = w_diag[(o*32+i)*16+u]  (o = og*4+o_l)
// Phase 1: yT[i][q] = sum_{j<8} xp[8q+j][i]          (block sums, transposed)
// Phase 2: Z[o_l][u][p] = (1/256) sum_{i,q} w_off[(o*32+i)*512+u*32+(q^p)]*yT[i][q]
//          thread = (u,o_l,qq): partial over q in [qq*8, qq*8+8), all i.
//          reduce 4 qq-partials via LDS; fold in b1[o].
// Phase 3: out[s, perm[r], o] = z[o_l][r>>4][(r>>3)&1] + sum_i xp[r][i]*wdt[...]
//          thread = row r, float4 store over the block's 4 o's.
// ---------------------------------------------------------------------------
__global__ __launch_bounds__(256) void k_fused(const float* __restrict__ x,
                                               const int* __restrict__ perm,
                                               const float* __restrict__ w_off,
                                               const float* __restrict__ w_diag,
                                               const float* __restrict__ b1,
                                               float* __restrict__ out) {
    const int t = threadIdx.x;
    const int b = blockIdx.x;
    const int s  = b >> 3;
    const int og = b & 7;

    __shared__ int   perm_s[256];
    __shared__ float xp[256 * 36];      // 36 KB, padded stride (bank-conflict-free, 16B-aligned)
    __shared__ float yT[32 * 36];       // 4.5 KB, yT[i][q] padded
    __shared__ float wdt[16 * 128];     // 8 KB, wdt[u][o_l*32 + i]
    __shared__ float part[128 * 5];     // 2.5 KB, qq-partials (stride 5 vs bank conflicts)
    __shared__ float z_l[128];          // Z[o_l][u][p] with b1 folded in

    perm_s[t] = perm[t];
    __syncthreads();

    // ---- Phase 0a: stage xp (8 passes, 8 lanes per row -> 128B coalesced rows)
    {
        const int r0 = t >> 3;          // 0..31
        const int c  = (t & 7) * 4;
#pragma unroll
        for (int pass = 0; pass < 8; ++pass) {
            const int r = pass * 32 + r0;
            const float4 v = *(const float4*)(x + (s * N_ + perm_s[r]) * IN_ + c);
            *(float4*)&xp[r * 36 + c] = v;
        }
    }
    // ---- Phase 0b: stage wdt (fully coalesced 2KB-contiguous loads)
    {
        const int o_l = t >> 6;
        const int i   = (t >> 1) & 31;
        const int o   = og * 4 + o_l;
#pragma unroll
        for (int k = 0; k < 2; ++k) {
            const int uq = (t & 1) * 2 + k;      // 0..3, u-quad
            const float4 v = *(const float4*)(w_diag + (o * 32 + i) * 16 + uq * 4);
            wdt[(uq * 4 + 0) * 128 + o_l * 32 + i] = v.x;
            wdt[(uq * 4 + 1) * 128 + o_l * 32 + i] = v.y;
            wdt[(uq * 4 + 2) * 128 + o_l * 32 + i] = v.z;
            wdt[(uq * 4 + 3) * 128 + o_l * 32 + i] = v.w;
        }
    }
    __syncthreads();

    // ---- Phase 1: block sums, transposed store yT[i][q]
    {
        const int i  = t & 31;
        const int qb = t >> 5;          // 0..7
#pragma unroll
        for (int k = 0; k < 4; ++k) {
            const int q = qb * 4 + k;
            float sum = 0.f;
#pragma unroll
            for (int j = 0; j < 8; ++j)
                sum += xp[(8 * q + j) * 36 + i];
            yT[i * 36 + q] = sum;       // stride-36 write: <=4-way, 4 writes, negligible
        }
    }
    __syncthreads();

    // ---- Phase 2: Z partials.  thread = (u, o_l, qq)
    {
        const int u   = t & 15;
        const int o_l = (t >> 4) & 3;
        const int qq  = t >> 6;          // q-chunk of 8
        const int o   = og * 4 + o_l;
        const float* wbase = w_off + ((o * 32) * 16 + u) * 32 + qq * 8;
        const float* yb    = yT + qq * 8;
        float p0 = 0.f, p1 = 0.f;
#pragma unroll
        for (int i = 0; i < 32; ++i) {
            const float4 w0 = *(const float4*)(wbase + i * 512);
            const float4 w1 = *(const float4*)(wbase + i * 512 + 4);
            const float4 ya = *(const float4*)(yb + i * 36);       // broadcast reads
            const float4 yc = *(const float4*)(yb + i * 36 + 4);
            p0 += w0.x*ya.x + w0.y*ya.y + w0.z*ya.z + w0.w*ya.w
                + w1.x*yc.x + w1.y*yc.y + w1.z*yc.z + w1.w*yc.w;
            // p=1 uses column q^1: swap adjacent w components
            p1 += w0.y*ya.x + w0.x*ya.y + w0.w*ya.z + w0.z*ya.w
                + w1.y*yc.x + w1.x*yc.y + w1.w*yc.z + w1.z*yc.w;
        }
        const int slot = (o_l * 16 + u) * 2;
        part[(slot + 0) * 5 + qq] = p0;
        part[(slot + 1) * 5 + qq] = p1;
    }
    __syncthreads();

    if (t < 128) {
        const float sum = part[t * 5 + 0] + part[t * 5 + 1]
                        + part[t * 5 + 2] + part[t * 5 + 3];
        const int o_l = t >> 5;
        z_l[t] = sum * (1.0f / 256.0f) + b1[og * 4 + o_l];
    }
    __syncthreads();

    // ---- Phase 3: epilogue.  thread = row r.
    {
        const int r = t;
        const int u = r >> 4;
        const int p = (r >> 3) & 1;
        const float4* xr = (const float4*)&xp[r * 36];
        float4 xv[8];
#pragma unroll
        for (int ii = 0; ii < 8; ++ii) xv[ii] = xr[ii];

        float acc[4];
#pragma unroll
        for (int o_l = 0; o_l < 4; ++o_l) {
            float a = z_l[(o_l * 16 + u) * 2 + p];
            const float4* wr = (const float4*)&wdt[u * 128 + o_l * 32];
#pragma unroll
            for (int ii = 0; ii < 8; ++ii) {
                const float4 w = wr[ii];
                a += xv[ii].x*w.x + xv[ii].y*w.y + xv[ii].z*w.z + xv[ii].w*w.w;
            }
            acc[o_l] = a;
        }
        const float4 res = make_float4(acc[0], acc[1], acc[2], acc[3]);
        *(float4*)(out + (s * N_ + perm_s[r]) * OUT_ + og * 4) = res;
    }
}

// ---------------------------------------------------------------------------
extern "C" void kernel_launch(void* const* d_in, const int* in_sizes, int n_in,
                              void* d_out, int out_size, void* d_ws, size_t ws_size,
                              hipStream_t stream) {
    const float* x      = (const float*)d_in[0];   // (32, 256, 32)
    const float* w_diag = (const float*)d_in[1];   // (1024, 16)
    const float* w_off  = (const float*)d_in[2];   // (1024, 16, 32)
    const float* b1     = (const float*)d_in[3];   // (32,)
    const int*   perm   = (const int*)d_in[4];     // (256,)
    // d_in[5] = inv_permute: not needed (scatter via perm, a bijection)
    // d_ws: deliberately UNUSED — Z stays in LDS (single fused kernel)

    float* out = (float*)d_out;
    k_fused<<<256, 256, 0, stream>>>(x, perm, w_off, w_diag, b1, out);
}

// Round 2
// 69.550 us; speedup vs baseline: 1.0902x; 1.0760x over previous
//
#include <hip/hip_runtime.h>

#define N_   256
#define IN_  32
#define OUT_ 32
#define BS_  32

// ---------------------------------------------------------------------------
// Fully fused kernel, high-occupancy version.
// grid 256 = (s: 32) x (og: 8 groups of 4 output channels).  1024 threads
// (16 waves/CU, 4 waves/SIMD — grid is 1 block/CU, so LDS is free but
// thread count is the only occupancy lever).
//
// Phase 0a: xp[r][i] = x[s, perm[r], i]        (stride-36 rows, 16B aligned)
// Phase 0b: wdt[(u*4+o_l)*36 + i] = w_diag[(o*32+i)*16 + u]
// Phase A : yT[i][q] = sum_{j<8} xp[8q+j][i]   (1024 threads = one (i,q) each)
// Phase B : Z[o_l][u][p] = (1/256) sum_{i,q} w_off[(o*32+i)*512+u*32+(q^p)]*yT[i][q]
//           thread = (qq,u,o_l,ih): q-chunk of 4, i-half of 16.
//           Wave lanes = (qq 0..7, u 8 consecutive) -> 1 KB CONTIGUOUS w_off
//           per instruction (fully coalesced), yT broadcast per 8 lanes.
//           16 partials/output reduced via LDS (stride 17, conflict-free).
// Phase C : out[s, perm[r], o] = z[o_l][u][p] + sum_i xp[r][i]*wdt[u][o_l][i]
//           thread = (r, o_l); 4 lanes/row -> 16B contiguous stores.
// ---------------------------------------------------------------------------
__global__ __launch_bounds__(1024) void k_fused(const float* __restrict__ x,
                                                const int* __restrict__ perm,
                                                const float* __restrict__ w_off,
                                                const float* __restrict__ w_diag,
                                                const float* __restrict__ b1,
                                                float* __restrict__ out) {
    const int t = threadIdx.x;
    const int b = blockIdx.x;
    const int s  = b >> 3;
    const int og = b & 7;

    __shared__ int   perm_s[256];
    __shared__ float xp[256 * 36];     // 36 KB
    __shared__ float yT[32 * 36];      // 4.5 KB   yT[i*36 + q]
    __shared__ float wdt[64 * 36];     // 9 KB     wdt[(u*4+o_l)*36 + i]
    __shared__ float part[128 * 17];   // 8.5 KB   odd stride: conflict-free reduce
    __shared__ float z_l[128];         // Z with b1 folded in

    if (t < 256) perm_s[t] = perm[t];
    __syncthreads();

    // ---- Phase 0a: stage xp (8 lanes per row -> 128B coalesced row reads)
    {
        const int c4 = t & 7;
        const int r0 = t >> 3;          // 0..127
#pragma unroll
        for (int pass = 0; pass < 2; ++pass) {
            const int r = pass * 128 + r0;
            const float4 v = *(const float4*)(x + (s * N_ + perm_s[r]) * IN_ + c4 * 4);
            *(float4*)&xp[r * 36 + c4 * 4] = v;
        }
    }
    // ---- Phase 0b: stage wdt (contiguous 16B/lane loads, transposed scatter)
    if (t < 512) {
        const int uq  = t & 3;          // u-quad
        const int row = t >> 2;         // 0..127 = o_l*32 + i
        const int o_l = row >> 5;
        const int i   = row & 31;
        const int o   = og * 4 + o_l;
        const float4 v = *(const float4*)(w_diag + (o * 32 + i) * 16 + uq * 4);
        wdt[((uq * 4 + 0) * 4 + o_l) * 36 + i] = v.x;
        wdt[((uq * 4 + 1) * 4 + o_l) * 36 + i] = v.y;
        wdt[((uq * 4 + 2) * 4 + o_l) * 36 + i] = v.z;
        wdt[((uq * 4 + 3) * 4 + o_l) * 36 + i] = v.w;
    }
    __syncthreads();

    // ---- Phase A: block sums, one (i,q) per thread
    {
        const int i = t & 31;
        const int q = t >> 5;           // 0..31
        float sum = 0.f;
#pragma unroll
        for (int j = 0; j < 8; ++j)
            sum += xp[(8 * q + j) * 36 + i];
        yT[i * 36 + q] = sum;
    }
    __syncthreads();

    // ---- Phase B: Z partials.  thread = (qq, u, o_l, ih)
    {
        const int qq  = t & 7;          // q-chunk of 4 (fastest -> coalesced)
        const int u   = (t >> 3) & 15;
        const int o_l = (t >> 7) & 3;
        const int ih  = t >> 9;         // i-half
        const int o   = og * 4 + o_l;
        const float* wbase = w_off + ((o * 32 + ih * 16) * 16 + u) * 32 + qq * 4;
        const float* yb    = yT + (ih * 16) * 36 + qq * 4;
        float p0 = 0.f, p1 = 0.f;
#pragma unroll
        for (int ii = 0; ii < 16; ++ii) {
            const float4 w  = *(const float4*)(wbase + ii * 512);
            const float4 ya = *(const float4*)(yb + ii * 36);
            p0 += w.x * ya.x + w.y * ya.y + w.z * ya.z + w.w * ya.w;
            // p=1 uses column q^1: swap adjacent w components
            p1 += w.y * ya.x + w.x * ya.y + w.w * ya.z + w.z * ya.w;
        }
        const int slot = (o_l * 16 + u) * 2;
        const int k    = ih * 8 + qq;
        part[(slot + 0) * 17 + k] = p0;
        part[(slot + 1) * 17 + k] = p1;
    }
    __syncthreads();

    if (t < 128) {
        float sum = 0.f;
#pragma unroll
        for (int k = 0; k < 16; ++k) sum += part[t * 17 + k];
        z_l[t] = sum * (1.0f / 256.0f) + b1[og * 4 + (t >> 5)];
    }
    __syncthreads();

    // ---- Phase C: epilogue.  thread = (r, o_l)
    {
        const int o_l = t & 3;
        const int r   = t >> 2;
        const int u   = r >> 4;
        const int p   = (r >> 3) & 1;
        float acc = z_l[(o_l * 16 + u) * 2 + p];
        const float4* xr = (const float4*)&xp[r * 36];
        const float4* wr = (const float4*)&wdt[(u * 4 + o_l) * 36];
#pragma unroll
        for (int ii = 0; ii < 8; ++ii) {
            const float4 xv = xr[ii];   // broadcast across the 4 o_l lanes
            const float4 wv = wr[ii];   // distinct banks per o_l (stride 36)
            acc += xv.x * wv.x + xv.y * wv.y + xv.z * wv.z + xv.w * wv.w;
        }
        out[(s * N_ + perm_s[r]) * OUT_ + og * 4 + o_l] = acc;
    }
}

// ---------------------------------------------------------------------------
extern "C" void kernel_launch(void* const* d_in, const int* in_sizes, int n_in,
                              void* d_out, int out_size, void* d_ws, size_t ws_size,
                              hipStream_t stream) {
    const float* x      = (const float*)d_in[0];   // (32, 256, 32)
    const float* w_diag = (const float*)d_in[1];   // (1024, 16)
    const float* w_off  = (const float*)d_in[2];   // (1024, 16, 32)
    const float* b1     = (const float*)d_in[3];   // (32,)
    const int*   perm   = (const int*)d_in[4];     // (256,)
    // d_in[5] = inv_permute: not needed (scatter via perm, a bijection)
    // d_ws: unused — the harness poisons it unconditionally either way

    float* out = (float*)d_out;
    k_fused<<<256, 1024, 0, stream>>>(x, perm, w_off, w_diag, b1, out);
}